// Round 6
// baseline (7274.089 us; speedup 1.0000x reference)
//
#include <hip/hip_runtime.h>
#include <math.h>

#define B_  64
#define S_  512
#define E_  300
#define H_  256
#define G4_ 1024
#define T_  22
#define M_  (B_*S_)
#define C_  16              // LSTM time chunk
#define NCH (S_/C_)         // 32 chunks
#define CROWS (B_*C_)       // 1024 rows per chunk per dir
#define RCH 4096            // highway row chunk
#define START_ (T_-2)
#define STOP_  (T_-1)

__device__ __forceinline__ float sigf(float x){ return 1.f/(1.f+expf(-x)); }

// w_hh [1024,256] -> wT [256][1024] with wT[k][4*j+g] = w_hh[g*256+j][k]
__global__ __launch_bounds__(256) void wtr_kernel(const float* __restrict__ whh, float* __restrict__ wT){
  int tid = blockIdx.x*256 + threadIdx.x;
  if (tid >= H_*G4_) return;
  int k = tid >> 10;
  int r = tid & 1023;
  int j = r >> 2, gi = r & 3;
  wT[tid] = whh[(size_t)(gi*H_ + j)*H_ + k];
}

struct __align__(16) TileSmem {
  float As[16][68];
  float Bs[16][68];
  int   widx[64];
  float wmsk[64];
};

// 64x64 tile GEMM body on 256 logical threads.
// gather mode: local row r -> word/mask flat index (r/chunkC)*S_ + t0 + (r%chunkC)
__device__ __forceinline__ void gemm_tile_body(
    TileSmem& sm, int tid,
    const float* __restrict__ A,
    const int* __restrict__ word, const int* __restrict__ maskp, const float* __restrict__ emb,
    const float* __restrict__ W, const float* __restrict__ bias,
    float* __restrict__ C, int K, int N, int gather, int t0, int chunkC,
    int row0, int col0) {
  const int tn = tid & 15, tm = tid >> 4;
  if (gather) {
    if (tid < 64) {
      int r  = row0 + tid;
      int b  = r / chunkC;
      int tl = r % chunkC;
      int wr = b*S_ + t0 + tl;
      sm.widx[tid] = word[wr];
      sm.wmsk[tid] = (float)maskp[wr];
    }
    __syncthreads();
  }
  float acc[4][4];
  #pragma unroll
  for (int i=0;i<4;i++)
    #pragma unroll
    for (int j=0;j<4;j++) acc[i][j]=0.f;

  for (int k0 = 0; k0 < K; k0 += 16) {
    #pragma unroll
    for (int i = 0; i < 4; ++i) {
      const int li = tid + (i<<8);
      const int m  = li >> 4, kk = li & 15;
      const int kg = k0 + kk;
      float av = 0.f;
      if (kg < K) {
        if (gather) av = emb[(size_t)sm.widx[m]*K + kg] * sm.wmsk[m];
        else        av = A[(size_t)(row0+m)*K + kg];
      }
      sm.As[kk][m] = av;
      const int nc = col0 + m;
      sm.Bs[kk][m] = (kg < K && nc < N) ? W[(size_t)nc*K + kg] : 0.f;
    }
    __syncthreads();
    #pragma unroll
    for (int kk = 0; kk < 16; ++kk) {
      const float4 a = *(const float4*)&sm.As[kk][tm<<2];
      const float4 b = *(const float4*)&sm.Bs[kk][tn<<2];
      acc[0][0]=fmaf(a.x,b.x,acc[0][0]); acc[0][1]=fmaf(a.x,b.y,acc[0][1]);
      acc[0][2]=fmaf(a.x,b.z,acc[0][2]); acc[0][3]=fmaf(a.x,b.w,acc[0][3]);
      acc[1][0]=fmaf(a.y,b.x,acc[1][0]); acc[1][1]=fmaf(a.y,b.y,acc[1][1]);
      acc[1][2]=fmaf(a.y,b.z,acc[1][2]); acc[1][3]=fmaf(a.y,b.w,acc[1][3]);
      acc[2][0]=fmaf(a.z,b.x,acc[2][0]); acc[2][1]=fmaf(a.z,b.y,acc[2][1]);
      acc[2][2]=fmaf(a.z,b.z,acc[2][2]); acc[2][3]=fmaf(a.z,b.w,acc[2][3]);
      acc[3][0]=fmaf(a.w,b.x,acc[3][0]); acc[3][1]=fmaf(a.w,b.y,acc[3][1]);
      acc[3][2]=fmaf(a.w,b.z,acc[3][2]); acc[3][3]=fmaf(a.w,b.w,acc[3][3]);
    }
    __syncthreads();
  }
  #pragma unroll
  for (int i=0;i<4;i++){
    const int r = row0 + (tm<<2) + i;
    #pragma unroll
    for (int j=0;j<4;j++){
      const int c = col0 + (tn<<2) + j;
      if (c < N) C[(size_t)r*N + c] = acc[i][j] + bias[c];
    }
  }
}

__global__ __launch_bounds__(256) void gemm_tiled(
    const float* __restrict__ A,
    const int* __restrict__ word, const int* __restrict__ maskp, const float* __restrict__ emb,
    const float* __restrict__ W, const float* __restrict__ bias,
    float* __restrict__ C, int K, int N, int gather, int t0, int chunkC) {
  __shared__ TileSmem sm;
  gemm_tile_body(sm, threadIdx.x, A, word, maskp, emb, W, bias, C, K, N,
                 gather, t0, chunkC, blockIdx.x << 6, blockIdx.y << 6);
}

// Input-projection gates for one chunk, both dirs (blockIdx.z = dir). grid (16,16,2).
__global__ __launch_bounds__(256) void gemm_gates(
    const int* __restrict__ word, const int* __restrict__ maskp, const float* __restrict__ emb,
    const float* __restrict__ w_ih_f, const float* __restrict__ b_f,
    const float* __restrict__ w_ih_b, const float* __restrict__ b_b,
    float* __restrict__ gout, int t0f, int t0b) {
  __shared__ TileSmem sm;
  const int dir = blockIdx.z;
  gemm_tile_body(sm, threadIdx.x, nullptr, word, maskp, emb,
                 dir ? w_ih_b : w_ih_f, dir ? b_b : b_f,
                 gout + (size_t)dir * CROWS * G4_, E_, G4_, 1,
                 dir ? t0b : t0f, C_, blockIdx.x << 6, blockIdx.y << 6);
}

// Recurrence only: 64 blocks x 512 threads; block = 2 batch x 1 dir; k-split 2.
// Gate loads hoisted before the k-loop; k-loop unrolled 16 for outstanding loads.
__global__ __launch_bounds__(512) void lstm_rec(
    const float* __restrict__ gall,
    const float* __restrict__ wTf, const float* __restrict__ wTb,
    float* __restrict__ h_bi, float* __restrict__ stH, float* __restrict__ stC,
    int t0f, int t0b, int first) {
  const int bid = blockIdx.x;
  const int tid = threadIdx.x;
  const int dir = bid & 1;
  const float* __restrict__ g  = gall + (size_t)dir * CROWS * G4_;
  const float* __restrict__ wT = dir ? wTb : wTf;
  const int b0 = (bid >> 1) * 2;
  const int hoff = dir ? H_ : 0;
  const int col = tid & 255;     // hidden index j
  const int kh  = tid >> 8;      // k-half
  __shared__ float hp[H_][2];
  __shared__ float psum[256][9];
  float c0 = 0.f, c1 = 0.f;
  if (kh == 0) {
    if (first) {
      hp[col][0] = 0.f; hp[col][1] = 0.f;
    } else {
      hp[col][0] = stH[((size_t)(dir*B_ + b0))*H_ + col];
      hp[col][1] = stH[((size_t)(dir*B_ + b0 + 1))*H_ + col];
      c0 = stC[((size_t)(dir*B_ + b0))*H_ + col];
      c1 = stC[((size_t)(dir*B_ + b0 + 1))*H_ + col];
    }
  }
  __syncthreads();
  const int kbase = kh << 7;
  for (int sl = 0; sl < C_; ++sl) {
    const int t  = dir ? (t0b + C_ - 1 - sl) : (t0f + sl);
    const int tl = dir ? (C_ - 1 - sl) : sl;
    // hoist gate loads: issued here, consumed after the k-loop (latency hidden)
    const size_t r0 = ((size_t)(b0*C_ + tl)) << 10;
    const size_t r1 = ((size_t)((b0+1)*C_ + tl)) << 10;
    const float gi0 = g[r0 + col];
    const float gf0 = g[r0 + H_ + col];
    const float gg0 = g[r0 + 2*H_ + col];
    const float go0 = g[r0 + 3*H_ + col];
    const float gi1 = g[r1 + col];
    const float gf1 = g[r1 + H_ + col];
    const float gg1 = g[r1 + 2*H_ + col];
    const float go1 = g[r1 + 3*H_ + col];
    float a0=0.f,a1=0.f,a2=0.f,a3=0.f,a4=0.f,a5=0.f,a6=0.f,a7=0.f;
    #pragma unroll 16
    for (int ku = 0; ku < 128; ++ku) {
      const int k = kbase + ku;
      const float4 w = *(const float4*)(wT + ((k<<10) + (col<<2)));
      const float h0 = hp[k][0], h1 = hp[k][1];
      a0 = fmaf(w.x, h0, a0); a1 = fmaf(w.y, h0, a1);
      a2 = fmaf(w.z, h0, a2); a3 = fmaf(w.w, h0, a3);
      a4 = fmaf(w.x, h1, a4); a5 = fmaf(w.y, h1, a5);
      a6 = fmaf(w.z, h1, a6); a7 = fmaf(w.w, h1, a7);
    }
    if (kh == 1) {
      psum[col][0]=a0; psum[col][1]=a1; psum[col][2]=a2; psum[col][3]=a3;
      psum[col][4]=a4; psum[col][5]=a5; psum[col][6]=a6; psum[col][7]=a7;
    }
    __syncthreads();
    if (kh == 0) {
      const float i0 = sigf(gi0 + a0 + psum[col][0]);
      const float f0 = sigf(gf0 + a1 + psum[col][1]);
      const float z0 = tanhf(gg0 + a2 + psum[col][2]);
      const float o0 = sigf(go0 + a3 + psum[col][3]);
      c0 = f0*c0 + i0*z0;
      const float hn0 = o0 * tanhf(c0);
      const float i1 = sigf(gi1 + a4 + psum[col][4]);
      const float f1 = sigf(gf1 + a5 + psum[col][5]);
      const float z1 = tanhf(gg1 + a6 + psum[col][6]);
      const float o1 = sigf(go1 + a7 + psum[col][7]);
      c1 = f1*c1 + i1*z1;
      const float hn1 = o1 * tanhf(c1);
      hp[col][0] = hn0; hp[col][1] = hn1;
      h_bi[((size_t)(b0*S_ + t))*(2*H_) + hoff + col] = hn0;
      h_bi[((size_t)((b0+1)*S_ + t))*(2*H_) + hoff + col] = hn1;
    }
    __syncthreads();
  }
  if (kh == 0) {
    stH[((size_t)(dir*B_ + b0))*H_ + col]     = hp[col][0];
    stH[((size_t)(dir*B_ + b0 + 1))*H_ + col] = hp[col][1];
    stC[((size_t)(dir*B_ + b0))*H_ + col]     = c0;
    stC[((size_t)(dir*B_ + b0 + 1))*H_ + col] = c1;
  }
}

// in-place highway over one row chunk
__global__ __launch_bounds__(256) void highway_kernel(
    const float* __restrict__ proj, float* __restrict__ h) {
  int idx = blockIdx.x*256 + threadIdx.x;
  int m = idx >> 9, j = idx & 511;
  float nl = proj[((size_t)m<<10) + j];
  float gt = proj[((size_t)m<<10) + 512 + j];
  float hv = h[idx];
  float gv = sigf(gt);
  h[idx] = gv*hv + (1.f-gv)*fmaxf(nl, 0.f);
}

__global__ __launch_bounds__(256) void gold_kernel(
    const int* __restrict__ labels, const int* __restrict__ maskp,
    const float* __restrict__ emitp, const float* __restrict__ trans, double* __restrict__ gold) {
  const int b = blockIdx.x; const int tid = threadIdx.x;
  double acc = 0.0; int len = 0;
  for (int t = tid; t < S_; t += 256) {
    int mk = maskp[b*S_ + t];
    len += mk;
    if (mk) {
      int lab  = labels[b*S_ + t];
      int prev = (t==0) ? START_ : labels[b*S_ + t - 1];
      acc += (double)trans[prev*T_ + lab] + (double)emitp[((size_t)b*S_ + t)*T_ + lab];
    }
  }
  __shared__ double sacc[256]; __shared__ int slen[256];
  sacc[tid]=acc; slen[tid]=len; __syncthreads();
  for (int s=128; s>0; s>>=1){ if (tid<s){ sacc[tid]+=sacc[tid+s]; slen[tid]+=slen[tid+s]; } __syncthreads(); }
  if (tid==0){
    int L = slen[0];
    int last = labels[b*S_ + L - 1];
    gold[b] = sacc[0] + (double)trans[last*T_ + STOP_];
  }
}

// Fused CRF-forward (role 0) + Viterbi (role 1). One wave per (batch, role).
__global__ __launch_bounds__(64) void crf_vit_kernel(
    const float* __restrict__ emitp, const float* __restrict__ trans,
    const int* __restrict__ maskp, double* __restrict__ fwd, float* __restrict__ out_tags) {
  const int b = blockIdx.x;
  const int role = blockIdx.y;
  const int lane = threadIdx.x;
  const int k = lane & 31, p = lane >> 5;
  const int kk = (k < T_) ? k : 0;

  if (role == 0) {
    __shared__ float trs[T_*T_];
    __shared__ double al[T_];
    for (int i = lane; i < T_*T_; i += 64) trs[i] = trans[i];
    __syncthreads();
    if (lane < T_) al[lane] = (double)emitp[(size_t)b*S_*T_ + lane] + (double)trs[START_*T_ + lane];
    __syncthreads();
    float ce = emitp[((size_t)b*S_ + 1)*T_ + kk];
    int   cm = maskp[b*S_ + 1];
    for (int t = 1; t < S_; ++t) {
      float ne = 0.f; int nm = 0;
      if (t+1 < S_) { ne = emitp[((size_t)b*S_ + t + 1)*T_ + kk]; nm = maskp[b*S_ + t + 1]; }
      double tj[11];
      #pragma unroll
      for (int u = 0; u < 11; ++u) {
        const int j = p*11 + u;
        tj[u] = al[j] + (double)trs[j*T_ + kk];
      }
      double m = tj[0];
      #pragma unroll
      for (int u = 1; u < 11; ++u) m = fmax(m, tj[u]);
      m = fmax(m, __shfl_xor(m, 32));
      float s = 0.f;
      #pragma unroll
      for (int u = 0; u < 11; ++u) s += __expf((float)(tj[u] - m));
      s += __shfl_xor(s, 32);
      const double nv = m + (double)__logf(s) + (double)ce;
      __syncthreads();
      if (cm && p == 0 && k < T_) al[k] = nv;
      __syncthreads();
      ce = ne; cm = nm;
    }
    if (lane == 0) {
      double mx = -1e300;
      for (int j = 0; j < T_; ++j) mx = fmax(mx, al[j] + (double)trs[j*T_ + STOP_]);
      double s = 0.0;
      for (int j = 0; j < T_; ++j) s += exp(al[j] + (double)trs[j*T_ + STOP_] - mx);
      fwd[b] = mx + log(s);
    }
  } else {
    __shared__ double tr64[T_*T_];
    __shared__ double dl[T_];
    __shared__ unsigned char bp[S_][T_];
    __shared__ int msk[S_];
    for (int i = lane; i < T_*T_; i += 64) tr64[i] = (double)trans[i];
    __syncthreads();
    if (lane < T_) dl[lane] = (double)emitp[(size_t)b*S_*T_ + lane] + tr64[START_*T_ + lane];
    if (lane == 0) msk[0] = maskp[b*S_];
    __syncthreads();
    float ce = emitp[((size_t)b*S_ + 1)*T_ + kk];
    int   cm = maskp[b*S_ + 1];
    for (int t = 1; t < S_; ++t) {
      float ne = 0.f; int nm = 0;
      if (t+1 < S_) { ne = emitp[((size_t)b*S_ + t + 1)*T_ + kk]; nm = maskp[b*S_ + t + 1]; }
      double best = dl[p*11] + tr64[(p*11)*T_ + kk];
      int arg = p*11;
      #pragma unroll
      for (int u = 1; u < 11; ++u) {
        const int j = p*11 + u;
        const double sc = dl[j] + tr64[j*T_ + kk];
        if (sc > best) { best = sc; arg = j; }
      }
      const double ob = __shfl_xor(best, 32);
      const int    oa = __shfl_xor(arg, 32);
      if (p == 0 && ob > best) { best = ob; arg = oa; }
      __syncthreads();
      if (p == 0 && k < T_) {
        if (cm) { dl[k] = best + (double)ce; bp[t][k] = (unsigned char)arg; }
        else    { bp[t][k] = (unsigned char)k; }
      }
      if (lane == 0) msk[t] = cm;
      __syncthreads();
      ce = ne; cm = nm;
    }
    if (lane == 0) {
      double bb = dl[0] + tr64[STOP_]; int cur = 0;
      for (int j = 1; j < T_; ++j) { const double sc = dl[j] + tr64[j*T_ + STOP_]; if (sc > bb) { bb = sc; cur = j; } }
      for (int t = S_-1; ; --t) {
        out_tags[b*S_ + t] = (float)(cur * msk[t]);
        if (t == 0) break;
        cur = bp[t][cur];
      }
    }
  }
}

__global__ void finalize_kernel(const double* __restrict__ fwd, const double* __restrict__ gold, float* __restrict__ out){
  if (threadIdx.x == 0 && blockIdx.x == 0) {
    double s = 0.0, g = 0.0;
    for (int b = 0; b < B_; ++b) { s += fwd[b]; g += gold[b]; }
    out[0] = (float)((s - g) / (double)B_);
  }
}

extern "C" void kernel_launch(void* const* d_in, const int* in_sizes, int n_in,
                              void* d_out, int out_size, void* d_ws, size_t ws_size,
                              hipStream_t stream) {
  const int*   word   = (const int*)d_in[0];
  const int*   maskp  = (const int*)d_in[1];
  const int*   labels = (const int*)d_in[2];
  const float* emb    = (const float*)d_in[3];
  const float* w_ih_f = (const float*)d_in[4];
  const float* w_hh_f = (const float*)d_in[5];
  const float* b_f    = (const float*)d_in[6];
  const float* w_ih_b = (const float*)d_in[7];
  const float* w_hh_b = (const float*)d_in[8];
  const float* b_b    = (const float*)d_in[9];
  const float* hw_W   = (const float*)d_in[10];
  const float* hw_b   = (const float*)d_in[11];
  const float* out_W  = (const float*)d_in[12];
  const float* out_b  = (const float*)d_in[13];
  const float* trans  = (const float*)d_in[14];
  float* out = (float*)d_out;

  // workspace layout (~89 MB, known good)
  float* h_bi  = (float*)d_ws;                          // [32768,512] -> h2 in place
  float* buf0  = h_bi + 16777216ULL;                    // [2,1024,1024] gates (also highway proj, spills into buf1)
  float* buf1  = buf0 + 2097152ULL;                     // [2,1024,1024]
  float* wTf   = buf1 + 2097152ULL;                     // [256,1024]
  float* wTb   = wTf + 262144ULL;                       // [256,1024]
  float* emitp = wTb + 262144ULL;                       // [32768,22]
  float* stH   = emitp + 720896ULL;                     // [2,64,256]
  float* stC   = stH + 32768ULL;                        // [2,64,256]
  double* fwdp = (double*)(stC + 32768ULL);             // [64]
  double* goldp = fwdp + 64;                            // [64]

  wtr_kernel<<<1024, 256, 0, stream>>>(w_hh_f, wTf);
  wtr_kernel<<<1024, 256, 0, stream>>>(w_hh_b, wTb);

  // chunked: gates GEMM (full GPU) then recurrence, serialized for attribution
  for (int i = 0; i < NCH; ++i) {
    const int t0f = i * C_;
    const int t0b = S_ - (i + 1) * C_;
    gemm_gates<<<dim3(CROWS/64, 16, 2), 256, 0, stream>>>(
        word, maskp, emb, w_ih_f, b_f, w_ih_b, b_b, buf0, t0f, t0b);
    lstm_rec<<<64, 512, 0, stream>>>(
        buf0, wTf, wTb, h_bi, stH, stC, t0f, t0b, (i == 0) ? 1 : 0);
  }

  // highway in row chunks (proj into buf0..buf1 contiguous), h2 in place
  for (int rc = 0; rc < M_ / RCH; ++rc) {
    float* Ach = h_bi + (size_t)rc * RCH * 512;
    gemm_tiled<<<dim3(RCH/64, 16), 256, 0, stream>>>(
        Ach, nullptr, nullptr, nullptr, hw_W, hw_b, buf0, 2*H_, G4_, 0, 0, C_);
    highway_kernel<<<(RCH*512)/256, 256, 0, stream>>>(buf0, Ach);
  }

  // emissions
  gemm_tiled<<<dim3(M_/64, 1), 256, 0, stream>>>(
      h_bi, nullptr, nullptr, nullptr, out_W, out_b, emitp, 2*H_, T_, 0, 0, C_);

  // CRF
  gold_kernel<<<64, 256, 0, stream>>>(labels, maskp, emitp, trans, goldp);
  crf_vit_kernel<<<dim3(64, 2), 64, 0, stream>>>(emitp, trans, maskp, fwdp, out + 1);
  finalize_kernel<<<1, 64, 0, stream>>>(fwdp, goldp, out);
}

// Round 7
// 7112.897 us; speedup vs baseline: 1.0227x; 1.0227x over previous
//
#include <hip/hip_runtime.h>
#include <math.h>

#define B_  64
#define S_  512
#define E_  300
#define H_  256
#define G4_ 1024
#define T_  22
#define M_  (B_*S_)
#define C_  16              // LSTM time chunk
#define NCH (S_/C_)         // 32 chunks
#define CROWS (B_*C_)       // 1024 rows per chunk per dir
#define RCH 4096            // highway row chunk
#define NBB 4               // batches per recurrence block
#define START_ (T_-2)
#define STOP_  (T_-1)

__device__ __forceinline__ float sigf(float x){ return 1.f/(1.f+expf(-x)); }

// w_hh [1024,256] -> wT [256][1024] with wT[k][4*j+g] = w_hh[g*256+j][k]
__global__ __launch_bounds__(256) void wtr_kernel(const float* __restrict__ whh, float* __restrict__ wT){
  int tid = blockIdx.x*256 + threadIdx.x;
  if (tid >= H_*G4_) return;
  int k = tid >> 10;
  int r = tid & 1023;
  int j = r >> 2, gi = r & 3;
  wT[tid] = whh[(size_t)(gi*H_ + j)*H_ + k];
}

struct __align__(16) TileSmem {
  float As[16][68];
  float Bs[16][68];
  int   widx[64];
  float wmsk[64];
};

// 64x64 tile GEMM body on 256 logical threads.
__device__ __forceinline__ void gemm_tile_body(
    TileSmem& sm, int tid,
    const float* __restrict__ A,
    const int* __restrict__ word, const int* __restrict__ maskp, const float* __restrict__ emb,
    const float* __restrict__ W, const float* __restrict__ bias,
    float* __restrict__ C, int K, int N, int gather, int t0, int chunkC,
    int row0, int col0) {
  const int tn = tid & 15, tm = tid >> 4;
  if (gather) {
    if (tid < 64) {
      int r  = row0 + tid;
      int b  = r / chunkC;
      int tl = r % chunkC;
      int wr = b*S_ + t0 + tl;
      sm.widx[tid] = word[wr];
      sm.wmsk[tid] = (float)maskp[wr];
    }
    __syncthreads();
  }
  float acc[4][4];
  #pragma unroll
  for (int i=0;i<4;i++)
    #pragma unroll
    for (int j=0;j<4;j++) acc[i][j]=0.f;

  for (int k0 = 0; k0 < K; k0 += 16) {
    #pragma unroll
    for (int i = 0; i < 4; ++i) {
      const int li = tid + (i<<8);
      const int m  = li >> 4, kk = li & 15;
      const int kg = k0 + kk;
      float av = 0.f;
      if (kg < K) {
        if (gather) av = emb[(size_t)sm.widx[m]*K + kg] * sm.wmsk[m];
        else        av = A[(size_t)(row0+m)*K + kg];
      }
      sm.As[kk][m] = av;
      const int nc = col0 + m;
      sm.Bs[kk][m] = (kg < K && nc < N) ? W[(size_t)nc*K + kg] : 0.f;
    }
    __syncthreads();
    #pragma unroll
    for (int kk = 0; kk < 16; ++kk) {
      const float4 a = *(const float4*)&sm.As[kk][tm<<2];
      const float4 b = *(const float4*)&sm.Bs[kk][tn<<2];
      acc[0][0]=fmaf(a.x,b.x,acc[0][0]); acc[0][1]=fmaf(a.x,b.y,acc[0][1]);
      acc[0][2]=fmaf(a.x,b.z,acc[0][2]); acc[0][3]=fmaf(a.x,b.w,acc[0][3]);
      acc[1][0]=fmaf(a.y,b.x,acc[1][0]); acc[1][1]=fmaf(a.y,b.y,acc[1][1]);
      acc[1][2]=fmaf(a.y,b.z,acc[1][2]); acc[1][3]=fmaf(a.y,b.w,acc[1][3]);
      acc[2][0]=fmaf(a.z,b.x,acc[2][0]); acc[2][1]=fmaf(a.z,b.y,acc[2][1]);
      acc[2][2]=fmaf(a.z,b.z,acc[2][2]); acc[2][3]=fmaf(a.z,b.w,acc[2][3]);
      acc[3][0]=fmaf(a.w,b.x,acc[3][0]); acc[3][1]=fmaf(a.w,b.y,acc[3][1]);
      acc[3][2]=fmaf(a.w,b.z,acc[3][2]); acc[3][3]=fmaf(a.w,b.w,acc[3][3]);
    }
    __syncthreads();
  }
  #pragma unroll
  for (int i=0;i<4;i++){
    const int r = row0 + (tm<<2) + i;
    #pragma unroll
    for (int j=0;j<4;j++){
      const int c = col0 + (tn<<2) + j;
      if (c < N) C[(size_t)r*N + c] = acc[i][j] + bias[c];
    }
  }
}

__global__ __launch_bounds__(256) void gemm_tiled(
    const float* __restrict__ A,
    const int* __restrict__ word, const int* __restrict__ maskp, const float* __restrict__ emb,
    const float* __restrict__ W, const float* __restrict__ bias,
    float* __restrict__ C, int K, int N, int gather, int t0, int chunkC) {
  __shared__ TileSmem sm;
  gemm_tile_body(sm, threadIdx.x, A, word, maskp, emb, W, bias, C, K, N,
                 gather, t0, chunkC, blockIdx.x << 6, blockIdx.y << 6);
}

// Input-projection gates for one chunk, both dirs (blockIdx.z = dir). grid (16,16,2).
__global__ __launch_bounds__(256) void gemm_gates(
    const int* __restrict__ word, const int* __restrict__ maskp, const float* __restrict__ emb,
    const float* __restrict__ w_ih_f, const float* __restrict__ b_f,
    const float* __restrict__ w_ih_b, const float* __restrict__ b_b,
    float* __restrict__ gout, int t0f, int t0b) {
  __shared__ TileSmem sm;
  const int dir = blockIdx.z;
  gemm_tile_body(sm, threadIdx.x, nullptr, word, maskp, emb,
                 dir ? w_ih_b : w_ih_f, dir ? b_b : b_f,
                 gout + (size_t)dir * CROWS * G4_, E_, G4_, 1,
                 dir ? t0b : t0f, C_, blockIdx.x << 6, blockIdx.y << 6);
}

// LDS-resident-weight recurrence. 256 blocks x 256 threads, 1 block/CU (LDS 157.7KB).
// Block = (dir, col-slice cs of 32 h-cols, batch-quad bq of 4 batches).
// Group = (dir,bq): 8 cs blocks exchange h each step via agent-scope atomics + counter.
__global__ __launch_bounds__(256) void lstm_sync(
    const float* __restrict__ gall,
    const float* __restrict__ wTf, const float* __restrict__ wTb,
    float* __restrict__ h_bi, float* __restrict__ stH, float* __restrict__ stC,
    float* __restrict__ hx, int* __restrict__ cnt,
    int t0f, int t0b, int cbase, int first) {
  const int bid = blockIdx.x;
  const int tid = threadIdx.x;
  const int dir = bid & 1;
  const int cs  = (bid >> 1) & 7;
  const int bq  = bid >> 4;              // 0..15
  const int gidx = dir*16 + bq;          // 0..31
  const float* __restrict__ wT = dir ? wTb : wTf;
  const float* __restrict__ g  = gall + (size_t)dir * CROWS * G4_;
  const int hoff = dir ? H_ : 0;

  __shared__ __align__(16) float wlds[128][256];   // [lc][k], k XOR-swizzled by (lc>>2)&7
  __shared__ __align__(16) float hp[NBB][256];
  __shared__ float psum[8][128][5];                // [ks][lc][b] padded
  __shared__ float gbuf[NBB][4][32];

  // ---- load weight slice into LDS (once per chunk) ----
  for (int it = 0; it < 32; ++it) {
    const int idx = tid + (it << 8);     // 0..8191
    const int k  = idx >> 5;
    const int lq = idx & 31;
    const int sw = (lq & 7) << 2;
    const int kx = k ^ sw;
    const float4 w = *(const float4*)&wT[(size_t)k*G4_ + cs*128 + (lq<<2)];
    wlds[(lq<<2)+0][kx] = w.x;
    wlds[(lq<<2)+1][kx] = w.y;
    wlds[(lq<<2)+2][kx] = w.z;
    wlds[(lq<<2)+3][kx] = w.w;
  }
  // ---- init hp from stH (or zeros) ----
  #pragma unroll
  for (int it = 0; it < 4; ++it) {
    const int idx = tid + (it << 8);     // 0..1023
    const int b = idx >> 8, col = idx & 255;
    hp[b][col] = first ? 0.f : stH[((size_t)(dir*B_ + bq*4 + b))*H_ + col];
  }
  // cell state (threads 0..127 own (tb2=tid>>5, jl=tid&31))
  const int tb2 = tid >> 5;
  const int jl  = tid & 31;
  float creg = 0.f;
  if (!first && tid < 128)
    creg = stC[((size_t)(dir*B_ + bq*4 + tb2))*H_ + cs*32 + jl];
  __syncthreads();

  // FMA role mapping
  const int lcq = tid & 31;              // lc0 = lcq*4
  const int ks  = tid >> 5;              // 0..7 -> k0 = ks*32
  const int lc0 = lcq << 2;
  const int sw  = (lcq & 7) << 2;
  const int k0  = ks << 5;
  // gate prefetch mapping: this thread loads (b0,col) and (b0+2,col)
  const int gb0 = tid >> 7;              // 0..1
  const int gr  = tid & 127;
  const int ggi = gr >> 5, gjl = gr & 31;
  const size_t gcol = (size_t)ggi*256 + cs*32 + gjl;

  float* hxg_base = hx;

  for (int sl = 0; sl < C_; ++sl) {
    const int t  = dir ? (t0b + C_ - 1 - sl) : (t0f + sl);
    const int tl = dir ? (C_ - 1 - sl) : sl;
    const int par = (cbase + sl) & 1;
    // issue gate loads early (latency hidden under FMA)
    const float gv0 = g[(size_t)((bq*4 + gb0    )*C_ + tl)*G4_ + gcol];
    const float gv1 = g[(size_t)((bq*4 + gb0 + 2)*C_ + tl)*G4_ + gcol];

    float4 a0 = {0,0,0,0}, a1 = {0,0,0,0}, a2 = {0,0,0,0}, a3 = {0,0,0,0};
    #pragma unroll
    for (int kq = 0; kq < 8; ++kq) {
      const int k  = k0 + (kq << 2);
      const int kx = k ^ sw;
      const float4 w0 = *(const float4*)&wlds[lc0+0][kx];
      const float4 w1 = *(const float4*)&wlds[lc0+1][kx];
      const float4 w2 = *(const float4*)&wlds[lc0+2][kx];
      const float4 w3 = *(const float4*)&wlds[lc0+3][kx];
      const float4 h0 = *(const float4*)&hp[0][k];
      const float4 h1 = *(const float4*)&hp[1][k];
      const float4 h2 = *(const float4*)&hp[2][k];
      const float4 h3 = *(const float4*)&hp[3][k];
      a0.x = fmaf(w0.x,h0.x,fmaf(w0.y,h0.y,fmaf(w0.z,h0.z,fmaf(w0.w,h0.w,a0.x))));
      a0.y = fmaf(w0.x,h1.x,fmaf(w0.y,h1.y,fmaf(w0.z,h1.z,fmaf(w0.w,h1.w,a0.y))));
      a0.z = fmaf(w0.x,h2.x,fmaf(w0.y,h2.y,fmaf(w0.z,h2.z,fmaf(w0.w,h2.w,a0.z))));
      a0.w = fmaf(w0.x,h3.x,fmaf(w0.y,h3.y,fmaf(w0.z,h3.z,fmaf(w0.w,h3.w,a0.w))));
      a1.x = fmaf(w1.x,h0.x,fmaf(w1.y,h0.y,fmaf(w1.z,h0.z,fmaf(w1.w,h0.w,a1.x))));
      a1.y = fmaf(w1.x,h1.x,fmaf(w1.y,h1.y,fmaf(w1.z,h1.z,fmaf(w1.w,h1.w,a1.y))));
      a1.z = fmaf(w1.x,h2.x,fmaf(w1.y,h2.y,fmaf(w1.z,h2.z,fmaf(w1.w,h2.w,a1.z))));
      a1.w = fmaf(w1.x,h3.x,fmaf(w1.y,h3.y,fmaf(w1.z,h3.z,fmaf(w1.w,h3.w,a1.w))));
      a2.x = fmaf(w2.x,h0.x,fmaf(w2.y,h0.y,fmaf(w2.z,h0.z,fmaf(w2.w,h0.w,a2.x))));
      a2.y = fmaf(w2.x,h1.x,fmaf(w2.y,h1.y,fmaf(w2.z,h1.z,fmaf(w2.w,h1.w,a2.y))));
      a2.z = fmaf(w2.x,h2.x,fmaf(w2.y,h2.y,fmaf(w2.z,h2.z,fmaf(w2.w,h2.w,a2.z))));
      a2.w = fmaf(w2.x,h3.x,fmaf(w2.y,h3.y,fmaf(w2.z,h3.z,fmaf(w2.w,h3.w,a2.w))));
      a3.x = fmaf(w3.x,h0.x,fmaf(w3.y,h0.y,fmaf(w3.z,h0.z,fmaf(w3.w,h0.w,a3.x))));
      a3.y = fmaf(w3.x,h1.x,fmaf(w3.y,h1.y,fmaf(w3.z,h1.z,fmaf(w3.w,h1.w,a3.y))));
      a3.z = fmaf(w3.x,h2.x,fmaf(w3.y,h2.y,fmaf(w3.z,h2.z,fmaf(w3.w,h2.w,a3.z))));
      a3.w = fmaf(w3.x,h3.x,fmaf(w3.y,h3.y,fmaf(w3.z,h3.z,fmaf(w3.w,h3.w,a3.w))));
    }
    psum[ks][lc0+0][0]=a0.x; psum[ks][lc0+0][1]=a0.y; psum[ks][lc0+0][2]=a0.z; psum[ks][lc0+0][3]=a0.w;
    psum[ks][lc0+1][0]=a1.x; psum[ks][lc0+1][1]=a1.y; psum[ks][lc0+1][2]=a1.z; psum[ks][lc0+1][3]=a1.w;
    psum[ks][lc0+2][0]=a2.x; psum[ks][lc0+2][1]=a2.y; psum[ks][lc0+2][2]=a2.z; psum[ks][lc0+2][3]=a2.w;
    psum[ks][lc0+3][0]=a3.x; psum[ks][lc0+3][1]=a3.y; psum[ks][lc0+3][2]=a3.z; psum[ks][lc0+3][3]=a3.w;
    gbuf[gb0    ][ggi][gjl] = gv0;
    gbuf[gb0 + 2][ggi][gjl] = gv1;
    __syncthreads();

    if (tid < 128) {
      float pre[4];
      #pragma unroll
      for (int gi = 0; gi < 4; ++gi) {
        float s = gbuf[tb2][gi][jl];
        #pragma unroll
        for (int k2 = 0; k2 < 8; ++k2) s += psum[k2][(jl<<2)+gi][tb2];
        pre[gi] = s;
      }
      const float iv = sigf(pre[0]);
      const float fv = sigf(pre[1]);
      const float zv = tanhf(pre[2]);
      const float ov = sigf(pre[3]);
      creg = fv*creg + iv*zv;
      const float hn = ov * tanhf(creg);
      hp[tb2][cs*32 + jl] = hn;
      h_bi[((size_t)((bq*4+tb2)*S_ + t))*(2*H_) + hoff + cs*32 + jl] = hn;
      if (sl < C_-1) {
        __hip_atomic_store(&hxg_base[(((size_t)(gidx*2 + par))*NBB + tb2)*256 + cs*32 + jl],
                           hn, __ATOMIC_RELAXED, __HIP_MEMORY_SCOPE_AGENT);
      } else {
        stH[((size_t)(dir*B_ + bq*4 + tb2))*H_ + cs*32 + jl] = hn;
        stC[((size_t)(dir*B_ + bq*4 + tb2))*H_ + cs*32 + jl] = creg;
      }
    }
    if (sl == C_-1) break;

    __syncthreads();   // drains hx stores (vmcnt0) before signal
    if (tid == 0) {
      __hip_atomic_fetch_add(&cnt[gidx << 5], 1, __ATOMIC_RELEASE, __HIP_MEMORY_SCOPE_AGENT);
      const int target = (cbase + sl + 1) << 3;
      while (__hip_atomic_load(&cnt[gidx << 5], __ATOMIC_ACQUIRE, __HIP_MEMORY_SCOPE_AGENT) < target) {
        __builtin_amdgcn_s_sleep(1);
      }
    }
    __syncthreads();
    // gather full h from the group
    #pragma unroll
    for (int it = 0; it < 4; ++it) {
      const int idx = tid + (it << 8);
      const int b = idx >> 8, col = idx & 255;
      hp[b][col] = __hip_atomic_load(
          &hxg_base[(((size_t)(gidx*2 + par))*NBB + b)*256 + col],
          __ATOMIC_RELAXED, __HIP_MEMORY_SCOPE_AGENT);
    }
    __syncthreads();
  }
}

// in-place highway over one row chunk
__global__ __launch_bounds__(256) void highway_kernel(
    const float* __restrict__ proj, float* __restrict__ h) {
  int idx = blockIdx.x*256 + threadIdx.x;
  int m = idx >> 9, j = idx & 511;
  float nl = proj[((size_t)m<<10) + j];
  float gt = proj[((size_t)m<<10) + 512 + j];
  float hv = h[idx];
  float gv = sigf(gt);
  h[idx] = gv*hv + (1.f-gv)*fmaxf(nl, 0.f);
}

__global__ __launch_bounds__(256) void gold_kernel(
    const int* __restrict__ labels, const int* __restrict__ maskp,
    const float* __restrict__ emitp, const float* __restrict__ trans, double* __restrict__ gold) {
  const int b = blockIdx.x; const int tid = threadIdx.x;
  double acc = 0.0; int len = 0;
  for (int t = tid; t < S_; t += 256) {
    int mk = maskp[b*S_ + t];
    len += mk;
    if (mk) {
      int lab  = labels[b*S_ + t];
      int prev = (t==0) ? START_ : labels[b*S_ + t - 1];
      acc += (double)trans[prev*T_ + lab] + (double)emitp[((size_t)b*S_ + t)*T_ + lab];
    }
  }
  __shared__ double sacc[256]; __shared__ int slen[256];
  sacc[tid]=acc; slen[tid]=len; __syncthreads();
  for (int s=128; s>0; s>>=1){ if (tid<s){ sacc[tid]+=sacc[tid+s]; slen[tid]+=slen[tid+s]; } __syncthreads(); }
  if (tid==0){
    int L = slen[0];
    int last = labels[b*S_ + L - 1];
    gold[b] = sacc[0] + (double)trans[last*T_ + STOP_];
  }
}

// Fused CRF-forward (role 0) + Viterbi (role 1). One wave per (batch, role).
__global__ __launch_bounds__(64) void crf_vit_kernel(
    const float* __restrict__ emitp, const float* __restrict__ trans,
    const int* __restrict__ maskp, double* __restrict__ fwd, float* __restrict__ out_tags) {
  const int b = blockIdx.x;
  const int role = blockIdx.y;
  const int lane = threadIdx.x;
  const int k = lane & 31, p = lane >> 5;
  const int kk = (k < T_) ? k : 0;

  if (role == 0) {
    __shared__ float trs[T_*T_];
    __shared__ double al[T_];
    for (int i = lane; i < T_*T_; i += 64) trs[i] = trans[i];
    __syncthreads();
    if (lane < T_) al[lane] = (double)emitp[(size_t)b*S_*T_ + lane] + (double)trs[START_*T_ + lane];
    __syncthreads();
    float ce = emitp[((size_t)b*S_ + 1)*T_ + kk];
    int   cm = maskp[b*S_ + 1];
    for (int t = 1; t < S_; ++t) {
      float ne = 0.f; int nm = 0;
      if (t+1 < S_) { ne = emitp[((size_t)b*S_ + t + 1)*T_ + kk]; nm = maskp[b*S_ + t + 1]; }
      double tj[11];
      #pragma unroll
      for (int u = 0; u < 11; ++u) {
        const int j = p*11 + u;
        tj[u] = al[j] + (double)trs[j*T_ + kk];
      }
      double m = tj[0];
      #pragma unroll
      for (int u = 1; u < 11; ++u) m = fmax(m, tj[u]);
      m = fmax(m, __shfl_xor(m, 32));
      float s = 0.f;
      #pragma unroll
      for (int u = 0; u < 11; ++u) s += __expf((float)(tj[u] - m));
      s += __shfl_xor(s, 32);
      const double nv = m + (double)__logf(s) + (double)ce;
      __syncthreads();
      if (cm && p == 0 && k < T_) al[k] = nv;
      __syncthreads();
      ce = ne; cm = nm;
    }
    if (lane == 0) {
      double mx = -1e300;
      for (int j = 0; j < T_; ++j) mx = fmax(mx, al[j] + (double)trs[j*T_ + STOP_]);
      double s = 0.0;
      for (int j = 0; j < T_; ++j) s += exp(al[j] + (double)trs[j*T_ + STOP_] - mx);
      fwd[b] = mx + log(s);
    }
  } else {
    __shared__ double tr64[T_*T_];
    __shared__ double dl[T_];
    __shared__ unsigned char bp[S_][T_];
    __shared__ int msk[S_];
    for (int i = lane; i < T_*T_; i += 64) tr64[i] = (double)trans[i];
    __syncthreads();
    if (lane < T_) dl[lane] = (double)emitp[(size_t)b*S_*T_ + lane] + tr64[START_*T_ + lane];
    if (lane == 0) msk[0] = maskp[b*S_];
    __syncthreads();
    float ce = emitp[((size_t)b*S_ + 1)*T_ + kk];
    int   cm = maskp[b*S_ + 1];
    for (int t = 1; t < S_; ++t) {
      float ne = 0.f; int nm = 0;
      if (t+1 < S_) { ne = emitp[((size_t)b*S_ + t + 1)*T_ + kk]; nm = maskp[b*S_ + t + 1]; }
      double best = dl[p*11] + tr64[(p*11)*T_ + kk];
      int arg = p*11;
      #pragma unroll
      for (int u = 1; u < 11; ++u) {
        const int j = p*11 + u;
        const double sc = dl[j] + tr64[j*T_ + kk];
        if (sc > best) { best = sc; arg = j; }
      }
      const double ob = __shfl_xor(best, 32);
      const int    oa = __shfl_xor(arg, 32);
      if (p == 0 && ob > best) { best = ob; arg = oa; }
      __syncthreads();
      if (p == 0 && k < T_) {
        if (cm) { dl[k] = best + (double)ce; bp[t][k] = (unsigned char)arg; }
        else    { bp[t][k] = (unsigned char)k; }
      }
      if (lane == 0) msk[t] = cm;
      __syncthreads();
      ce = ne; cm = nm;
    }
    if (lane == 0) {
      double bb = dl[0] + tr64[STOP_]; int cur = 0;
      for (int j = 1; j < T_; ++j) { const double sc = dl[j] + tr64[j*T_ + STOP_]; if (sc > bb) { bb = sc; cur = j; } }
      for (int t = S_-1; ; --t) {
        out_tags[b*S_ + t] = (float)(cur * msk[t]);
        if (t == 0) break;
        cur = bp[t][cur];
      }
    }
  }
}

__global__ void finalize_kernel(const double* __restrict__ fwd, const double* __restrict__ gold, float* __restrict__ out){
  if (threadIdx.x == 0 && blockIdx.x == 0) {
    double s = 0.0, g = 0.0;
    for (int b = 0; b < B_; ++b) { s += fwd[b]; g += gold[b]; }
    out[0] = (float)((s - g) / (double)B_);
  }
}

extern "C" void kernel_launch(void* const* d_in, const int* in_sizes, int n_in,
                              void* d_out, int out_size, void* d_ws, size_t ws_size,
                              hipStream_t stream) {
  const int*   word   = (const int*)d_in[0];
  const int*   maskp  = (const int*)d_in[1];
  const int*   labels = (const int*)d_in[2];
  const float* emb    = (const float*)d_in[3];
  const float* w_ih_f = (const float*)d_in[4];
  const float* w_hh_f = (const float*)d_in[5];
  const float* b_f    = (const float*)d_in[6];
  const float* w_ih_b = (const float*)d_in[7];
  const float* w_hh_b = (const float*)d_in[8];
  const float* b_b    = (const float*)d_in[9];
  const float* hw_W   = (const float*)d_in[10];
  const float* hw_b   = (const float*)d_in[11];
  const float* out_W  = (const float*)d_in[12];
  const float* out_b  = (const float*)d_in[13];
  const float* trans  = (const float*)d_in[14];
  float* out = (float*)d_out;

  // workspace layout (~81 MB)
  float* h_bi  = (float*)d_ws;                          // [32768,512] -> h2 in place
  float* buf0  = h_bi + 16777216ULL;                    // [2,1024,1024] gates
  float* wTf   = buf0 + 2097152ULL;                     // [256,1024]
  float* wTb   = wTf + 262144ULL;                       // [256,1024]
  float* emitp = wTb + 262144ULL;                       // [32768,22]
  float* stH   = emitp + 720896ULL;                     // [2,64,256]
  float* stC   = stH + 32768ULL;                        // [2,64,256]
  float* hx    = stC + 32768ULL;                        // [32 groups][2 par][4 b][256]
  int*   cnt   = (int*)(hx + 65536ULL);                 // [32 groups x 32 stride]
  double* fwdp = (double*)(cnt + 1024);                 // [64]
  double* goldp = fwdp + 64;                            // [64]

  hipMemsetAsync(cnt, 0, 1024 * sizeof(int), stream);

  wtr_kernel<<<1024, 256, 0, stream>>>(w_hh_f, wTf);
  wtr_kernel<<<1024, 256, 0, stream>>>(w_hh_b, wTb);

  // chunked: gates GEMM (full GPU) then LDS-resident synced recurrence
  for (int i = 0; i < NCH; ++i) {
    const int t0f = i * C_;
    const int t0b = S_ - (i + 1) * C_;
    gemm_gates<<<dim3(CROWS/64, 16, 2), 256, 0, stream>>>(
        word, maskp, emb, w_ih_f, b_f, w_ih_b, b_b, buf0, t0f, t0b);
    lstm_sync<<<256, 256, 0, stream>>>(
        buf0, wTf, wTb, h_bi, stH, stC, hx, cnt,
        t0f, t0b, i * (C_ - 1), (i == 0) ? 1 : 0);
  }

  // highway in row chunks (proj into buf0 region), h2 in place
  for (int rc = 0; rc < M_ / RCH; ++rc) {
    float* Ach = h_bi + (size_t)rc * RCH * 512;
    gemm_tiled<<<dim3(RCH/64, 16), 256, 0, stream>>>(
        Ach, nullptr, nullptr, nullptr, hw_W, hw_b, buf0, 2*H_, G4_, 0, 0, C_);
    highway_kernel<<<(RCH*512)/256, 256, 0, stream>>>(buf0, Ach);
  }

  // emissions
  gemm_tiled<<<dim3(M_/64, 1), 256, 0, stream>>>(
      h_bi, nullptr, nullptr, nullptr, out_W, out_b, emitp, 2*H_, T_, 0, 0, C_);

  // CRF
  gold_kernel<<<64, 256, 0, stream>>>(labels, maskp, emitp, trans, goldp);
  crf_vit_kernel<<<dim3(64, 2), 64, 0, stream>>>(emitp, trans, maskp, fwdp, out + 1);
  finalize_kernel<<<1, 64, 0, stream>>>(fwdp, goldp, out);
}

// Round 8
// 4468.529 us; speedup vs baseline: 1.6278x; 1.5918x over previous
//
#include <hip/hip_runtime.h>
#include <hip/hip_fp16.h>
#include <math.h>

#define B_  64
#define S_  512
#define E_  300
#define H_  256
#define G4_ 1024
#define T_  22
#define M_  (B_*S_)
#define C_  16              // LSTM time chunk
#define NCH (S_/C_)         // 32 chunks
#define CROWS (B_*C_)       // 1024 rows per chunk per dir
#define RCH 4096            // highway row chunk
#define START_ (T_-2)
#define STOP_  (T_-1)

__device__ __forceinline__ float sigf(float x){ return 1.f/(1.f+expf(-x)); }

// w_hh [1024,256] -> wT16 [1024 col][256 k] fp16, col = 4*j + gate
__global__ __launch_bounds__(256) void wtr16_kernel(const float* __restrict__ whh, __half* __restrict__ wT){
  int tid = blockIdx.x*256 + threadIdx.x;
  if (tid >= H_*G4_) return;
  int col = tid >> 8, k = tid & 255;
  int j = col >> 2, gi = col & 3;
  wT[tid] = __float2half(whh[(size_t)(gi*H_ + j)*H_ + k]);
}

struct __align__(16) TileSmem {
  float As[16][68];
  float Bs[16][68];
  int   widx[64];
  float wmsk[64];
};

struct __align__(16) RecSmem {
  __half w[128][268];        // 68608 B, row 536B (8B-aligned); ~4-way conflict ok
  float  hp[4][256];         // 4096 B
  float  psum[2][4][32][5];  // 5120 B  [ks][gi][jl][b-pad5]
  float  gbuf[4][4][32];     // 2048 B  [b][gi][jl]
};                            // total 79,872 B -> 2 blocks/CU

union SmemU { RecSmem r; TileSmem t; };

// 64x64 tile GEMM body on 256 logical threads.
__device__ __forceinline__ void gemm_tile_body(
    TileSmem& sm, int tid,
    const float* __restrict__ A,
    const int* __restrict__ word, const int* __restrict__ maskp, const float* __restrict__ emb,
    const float* __restrict__ W, const float* __restrict__ bias,
    float* __restrict__ C, int K, int N, int gather, int t0, int chunkC,
    int row0, int col0) {
  const int tn = tid & 15, tm = tid >> 4;
  if (gather) {
    if (tid < 64) {
      int r  = row0 + tid;
      int b  = r / chunkC;
      int tl = r % chunkC;
      int wr = b*S_ + t0 + tl;
      sm.widx[tid] = word[wr];
      sm.wmsk[tid] = (float)maskp[wr];
    }
    __syncthreads();
  }
  float acc[4][4];
  #pragma unroll
  for (int i=0;i<4;i++)
    #pragma unroll
    for (int j=0;j<4;j++) acc[i][j]=0.f;

  for (int k0 = 0; k0 < K; k0 += 16) {
    #pragma unroll
    for (int i = 0; i < 4; ++i) {
      const int li = tid + (i<<8);
      const int m  = li >> 4, kk = li & 15;
      const int kg = k0 + kk;
      float av = 0.f;
      if (kg < K) {
        if (gather) av = emb[(size_t)sm.widx[m]*K + kg] * sm.wmsk[m];
        else        av = A[(size_t)(row0+m)*K + kg];
      }
      sm.As[kk][m] = av;
      const int nc = col0 + m;
      sm.Bs[kk][m] = (kg < K && nc < N) ? W[(size_t)nc*K + kg] : 0.f;
    }
    __syncthreads();
    #pragma unroll
    for (int kk = 0; kk < 16; ++kk) {
      const float4 a = *(const float4*)&sm.As[kk][tm<<2];
      const float4 b = *(const float4*)&sm.Bs[kk][tn<<2];
      acc[0][0]=fmaf(a.x,b.x,acc[0][0]); acc[0][1]=fmaf(a.x,b.y,acc[0][1]);
      acc[0][2]=fmaf(a.x,b.z,acc[0][2]); acc[0][3]=fmaf(a.x,b.w,acc[0][3]);
      acc[1][0]=fmaf(a.y,b.x,acc[1][0]); acc[1][1]=fmaf(a.y,b.y,acc[1][1]);
      acc[1][2]=fmaf(a.y,b.z,acc[1][2]); acc[1][3]=fmaf(a.y,b.w,acc[1][3]);
      acc[2][0]=fmaf(a.z,b.x,acc[2][0]); acc[2][1]=fmaf(a.z,b.y,acc[2][1]);
      acc[2][2]=fmaf(a.z,b.z,acc[2][2]); acc[2][3]=fmaf(a.z,b.w,acc[2][3]);
      acc[3][0]=fmaf(a.w,b.x,acc[3][0]); acc[3][1]=fmaf(a.w,b.y,acc[3][1]);
      acc[3][2]=fmaf(a.w,b.z,acc[3][2]); acc[3][3]=fmaf(a.w,b.w,acc[3][3]);
    }
    __syncthreads();
  }
  #pragma unroll
  for (int i=0;i<4;i++){
    const int r = row0 + (tm<<2) + i;
    #pragma unroll
    for (int j=0;j<4;j++){
      const int c = col0 + (tn<<2) + j;
      if (c < N) C[(size_t)r*N + c] = acc[i][j] + bias[c];
    }
  }
}

__global__ __launch_bounds__(256) void gemm_tiled(
    const float* __restrict__ A,
    const int* __restrict__ word, const int* __restrict__ maskp, const float* __restrict__ emb,
    const float* __restrict__ W, const float* __restrict__ bias,
    float* __restrict__ C, int K, int N, int gather, int t0, int chunkC) {
  __shared__ TileSmem sm;
  gemm_tile_body(sm, threadIdx.x, A, word, maskp, emb, W, bias, C, K, N,
                 gather, t0, chunkC, blockIdx.x << 6, blockIdx.y << 6);
}

// standalone gates GEMM for chunk 0
__global__ __launch_bounds__(256) void gemm_gates(
    const int* __restrict__ word, const int* __restrict__ maskp, const float* __restrict__ emb,
    const float* __restrict__ w_ih_f, const float* __restrict__ b_f,
    const float* __restrict__ w_ih_b, const float* __restrict__ b_b,
    float* __restrict__ gout, int t0f, int t0b) {
  __shared__ TileSmem sm;
  const int dir = blockIdx.z;
  gemm_tile_body(sm, threadIdx.x, nullptr, word, maskp, emb,
                 dir ? w_ih_b : w_ih_f, dir ? b_b : b_f,
                 gout + (size_t)dir * CROWS * G4_, E_, G4_, 1,
                 dir ? t0b : t0f, C_, blockIdx.x << 6, blockIdx.y << 6);
}

// Fused: bids [0,256) = recurrence (fp16 weights in LDS, fence-free u64-tag exchange);
//        bids [256,512) = next chunk's gates GEMM (2 tiles each), co-resident 1/CU.
__global__ __launch_bounds__(256) void lstm_mega(
    const float* __restrict__ gcur, float* __restrict__ gnext,
    const int* __restrict__ word, const int* __restrict__ maskp, const float* __restrict__ emb,
    const float* __restrict__ w_ih_f, const float* __restrict__ b_f,
    const float* __restrict__ w_ih_b, const float* __restrict__ b_b,
    const __half* __restrict__ wT16,
    float* __restrict__ h_bi, float* __restrict__ stH, float* __restrict__ stC,
    unsigned long long* __restrict__ hx,
    int t0f, int t0b, int n0f, int n0b, int ebase, int first) {
  __shared__ SmemU sm;
  const int bid = blockIdx.x;
  const int tid = threadIdx.x;

  if (bid >= 256) {
    if (n0f < 0) return;
    #pragma unroll 1
    for (int hfl = 0; hfl < 2; ++hfl) {
      const int tile = (bid - 256)*2 + hfl;      // 0..511
      const int dirg = tile >> 8;
      const int tt   = tile & 255;
      gemm_tile_body(sm.t, tid, nullptr, word, maskp, emb,
                     dirg ? w_ih_b : w_ih_f, dirg ? b_b : b_f,
                     gnext + (size_t)dirg * CROWS * G4_, E_, G4_, 1,
                     dirg ? n0b : n0f, C_, (tt & 15) << 6, (tt >> 4) << 6);
      __syncthreads();
    }
    return;
  }

  // ---- recurrence role ----
  const int dir = bid & 1;
  const int cs  = (bid >> 1) & 7;        // col-slice: 32 h-cols
  const int bq  = bid >> 4;              // batch-quad 0..15
  const int gidx = dir*16 + bq;          // group 0..31 (8 cs-blocks each)
  const float*  __restrict__ g    = gcur + (size_t)dir * CROWS * G4_;
  const __half* __restrict__ wsrc = wT16 + (size_t)dir * (G4_*H_);
  const int hoff = dir ? H_ : 0;

  // stage fp16 weight slice: cols [cs*128, +128) x 256 k
  for (int it = 0; it < 32; ++it) {
    const int idx = tid + (it << 8);     // 0..8191
    const int lc = idx >> 6;             // 0..127
    const int k0 = (idx & 63) << 2;      // 0..252
    const uint2 u = *(const uint2*)&wsrc[(size_t)(cs*128 + lc)*256 + k0];
    *(uint2*)&sm.r.w[lc][k0] = u;
  }
  for (int it = 0; it < 4; ++it) {
    const int idx = tid + (it << 8);
    const int b = idx >> 8, col = idx & 255;
    sm.r.hp[b][col] = first ? 0.f : stH[((size_t)(dir*B_ + bq*4 + b))*H_ + col];
  }
  const int ab  = tid >> 5;              // activation batch (tid<128)
  const int ajl = tid & 31;              // activation h-col-local
  float creg = 0.f;
  if (!first && tid < 128)
    creg = stC[((size_t)(dir*B_ + bq*4 + ab))*H_ + cs*32 + ajl];
  __syncthreads();

  const int ks = tid >> 7;               // k-half 0..1
  const int lc = tid & 127;              // gate-col-local
  const int gi = lc & 3, jl = lc >> 2;
  const int kb = ks << 7;
  const int gb0  = tid >> 7;             // gate prefetch mapping
  const int grem = tid & 127;
  const int ggi = grem >> 5, gjl = grem & 31;
  const size_t gcol = (size_t)ggi*256 + cs*32 + gjl;

  for (int sl = 0; sl < C_; ++sl) {
    const int t  = dir ? (t0b + C_-1-sl) : (t0f + sl);
    const int tl = dir ? (C_-1-sl) : sl;
    const float gv0 = g[(size_t)((bq*4 + gb0    )*C_ + tl)*G4_ + gcol];
    const float gv1 = g[(size_t)((bq*4 + gb0 + 2)*C_ + tl)*G4_ + gcol];

    float acc0=0.f, acc1=0.f, acc2=0.f, acc3=0.f;
    #pragma unroll 8
    for (int kq = 0; kq < 32; ++kq) {
      const int k0 = kb + (kq << 2);
      const uint2 u = *(const uint2*)&sm.r.w[lc][k0];
      __half2 p01, p23;
      *(unsigned*)&p01 = u.x; *(unsigned*)&p23 = u.y;
      const float2 f01 = __half22float2(p01);
      const float2 f23 = __half22float2(p23);
      const float4 h0 = *(const float4*)&sm.r.hp[0][k0];
      const float4 h1 = *(const float4*)&sm.r.hp[1][k0];
      const float4 h2 = *(const float4*)&sm.r.hp[2][k0];
      const float4 h3 = *(const float4*)&sm.r.hp[3][k0];
      acc0 = fmaf(f01.x,h0.x,fmaf(f01.y,h0.y,fmaf(f23.x,h0.z,fmaf(f23.y,h0.w,acc0))));
      acc1 = fmaf(f01.x,h1.x,fmaf(f01.y,h1.y,fmaf(f23.x,h1.z,fmaf(f23.y,h1.w,acc1))));
      acc2 = fmaf(f01.x,h2.x,fmaf(f01.y,h2.y,fmaf(f23.x,h2.z,fmaf(f23.y,h2.w,acc2))));
      acc3 = fmaf(f01.x,h3.x,fmaf(f01.y,h3.y,fmaf(f23.x,h3.z,fmaf(f23.y,h3.w,acc3))));
    }
    sm.r.psum[ks][gi][jl][0]=acc0; sm.r.psum[ks][gi][jl][1]=acc1;
    sm.r.psum[ks][gi][jl][2]=acc2; sm.r.psum[ks][gi][jl][3]=acc3;
    sm.r.gbuf[gb0    ][ggi][gjl] = gv0;
    sm.r.gbuf[gb0 + 2][ggi][gjl] = gv1;
    __syncthreads();

    const int e = ebase + sl;
    const int par = e & 1;
    const unsigned tag = (unsigned)(e + 1);
    if (tid < 128) {
      const float pre0 = sm.r.gbuf[ab][0][ajl] + sm.r.psum[0][0][ajl][ab] + sm.r.psum[1][0][ajl][ab];
      const float pre1 = sm.r.gbuf[ab][1][ajl] + sm.r.psum[0][1][ajl][ab] + sm.r.psum[1][1][ajl][ab];
      const float pre2 = sm.r.gbuf[ab][2][ajl] + sm.r.psum[0][2][ajl][ab] + sm.r.psum[1][2][ajl][ab];
      const float pre3 = sm.r.gbuf[ab][3][ajl] + sm.r.psum[0][3][ajl][ab] + sm.r.psum[1][3][ajl][ab];
      const float iv = sigf(pre0), fv = sigf(pre1);
      const float zv = tanhf(pre2), ov = sigf(pre3);
      creg = fv*creg + iv*zv;
      const float hn = ov * tanhf(creg);
      h_bi[((size_t)((bq*4+ab)*S_ + t))*(2*H_) + hoff + cs*32 + ajl] = hn;
      if (sl < C_-1) {
        const unsigned long long pk =
            ((unsigned long long)tag << 32) | (unsigned long long)__float_as_uint(hn);
        __hip_atomic_store(&hx[(((size_t)par*32 + gidx)*4 + ab)*256 + cs*32 + ajl], pk,
                           __ATOMIC_RELAXED, __HIP_MEMORY_SCOPE_AGENT);
      } else {
        stH[((size_t)(dir*B_ + bq*4 + ab))*H_ + cs*32 + ajl] = hn;
        stC[((size_t)(dir*B_ + bq*4 + ab))*H_ + cs*32 + ajl] = creg;
      }
    }
    if (sl == C_-1) break;

    // fence-free gather: poll u64 (tag|value), 4 in flight per thread
    {
      const unsigned long long* hb = &hx[((size_t)par*32 + gidx) << 10];
      float r0,r1,r2,r3;
      bool d0=false,d1=false,d2=false,d3=false;
      for (;;) {
        if (!d0) { unsigned long long v = __hip_atomic_load(hb + tid,       __ATOMIC_RELAXED, __HIP_MEMORY_SCOPE_AGENT);
                   if ((unsigned)(v>>32) == tag) { r0 = __uint_as_float((unsigned)v); d0 = true; } }
        if (!d1) { unsigned long long v = __hip_atomic_load(hb + 256 + tid, __ATOMIC_RELAXED, __HIP_MEMORY_SCOPE_AGENT);
                   if ((unsigned)(v>>32) == tag) { r1 = __uint_as_float((unsigned)v); d1 = true; } }
        if (!d2) { unsigned long long v = __hip_atomic_load(hb + 512 + tid, __ATOMIC_RELAXED, __HIP_MEMORY_SCOPE_AGENT);
                   if ((unsigned)(v>>32) == tag) { r2 = __uint_as_float((unsigned)v); d2 = true; } }
        if (!d3) { unsigned long long v = __hip_atomic_load(hb + 768 + tid, __ATOMIC_RELAXED, __HIP_MEMORY_SCOPE_AGENT);
                   if ((unsigned)(v>>32) == tag) { r3 = __uint_as_float((unsigned)v); d3 = true; } }
        if (d0 && d1 && d2 && d3) break;
        __builtin_amdgcn_s_sleep(1);
      }
      sm.r.hp[0][tid] = r0; sm.r.hp[1][tid] = r1;
      sm.r.hp[2][tid] = r2; sm.r.hp[3][tid] = r3;
    }
    __syncthreads();
  }
}

// in-place highway over one row chunk
__global__ __launch_bounds__(256) void highway_kernel(
    const float* __restrict__ proj, float* __restrict__ h) {
  int idx = blockIdx.x*256 + threadIdx.x;
  int m = idx >> 9, j = idx & 511;
  float nl = proj[((size_t)m<<10) + j];
  float gt = proj[((size_t)m<<10) + 512 + j];
  float hv = h[idx];
  float gv = sigf(gt);
  h[idx] = gv*hv + (1.f-gv)*fmaxf(nl, 0.f);
}

__global__ __launch_bounds__(256) void gold_kernel(
    const int* __restrict__ labels, const int* __restrict__ maskp,
    const float* __restrict__ emitp, const float* __restrict__ trans, double* __restrict__ gold) {
  const int b = blockIdx.x; const int tid = threadIdx.x;
  double acc = 0.0; int len = 0;
  for (int t = tid; t < S_; t += 256) {
    int mk = maskp[b*S_ + t];
    len += mk;
    if (mk) {
      int lab  = labels[b*S_ + t];
      int prev = (t==0) ? START_ : labels[b*S_ + t - 1];
      acc += (double)trans[prev*T_ + lab] + (double)emitp[((size_t)b*S_ + t)*T_ + lab];
    }
  }
  __shared__ double sacc[256]; __shared__ int slen[256];
  sacc[tid]=acc; slen[tid]=len; __syncthreads();
  for (int s=128; s>0; s>>=1){ if (tid<s){ sacc[tid]+=sacc[tid+s]; slen[tid]+=slen[tid+s]; } __syncthreads(); }
  if (tid==0){
    int L = slen[0];
    int last = labels[b*S_ + L - 1];
    gold[b] = sacc[0] + (double)trans[last*T_ + STOP_];
  }
}

// Fused CRF-forward (role 0) + Viterbi (role 1). One wave per (batch, role).
__global__ __launch_bounds__(64) void crf_vit_kernel(
    const float* __restrict__ emitp, const float* __restrict__ trans,
    const int* __restrict__ maskp, double* __restrict__ fwd, float* __restrict__ out_tags) {
  const int b = blockIdx.x;
  const int role = blockIdx.y;
  const int lane = threadIdx.x;
  const int k = lane & 31, p = lane >> 5;
  const int kk = (k < T_) ? k : 0;

  if (role == 0) {
    __shared__ float trs[T_*T_];
    __shared__ double al[T_];
    for (int i = lane; i < T_*T_; i += 64) trs[i] = trans[i];
    __syncthreads();
    if (lane < T_) al[lane] = (double)emitp[(size_t)b*S_*T_ + lane] + (double)trs[START_*T_ + lane];
    __syncthreads();
    float ce = emitp[((size_t)b*S_ + 1)*T_ + kk];
    int   cm = maskp[b*S_ + 1];
    for (int t = 1; t < S_; ++t) {
      float ne = 0.f; int nm = 0;
      if (t+1 < S_) { ne = emitp[((size_t)b*S_ + t + 1)*T_ + kk]; nm = maskp[b*S_ + t + 1]; }
      double tj[11];
      #pragma unroll
      for (int u = 0; u < 11; ++u) {
        const int j = p*11 + u;
        tj[u] = al[j] + (double)trs[j*T_ + kk];
      }
      double m = tj[0];
      #pragma unroll
      for (int u = 1; u < 11; ++u) m = fmax(m, tj[u]);
      m = fmax(m, __shfl_xor(m, 32));
      float s = 0.f;
      #pragma unroll
      for (int u = 0; u < 11; ++u) s += __expf((float)(tj[u] - m));
      s += __shfl_xor(s, 32);
      const double nv = m + (double)__logf(s) + (double)ce;
      __syncthreads();
      if (cm && p == 0 && k < T_) al[k] = nv;
      __syncthreads();
      ce = ne; cm = nm;
    }
    if (lane == 0) {
      double mx = -1e300;
      for (int j = 0; j < T_; ++j) mx = fmax(mx, al[j] + (double)trs[j*T_ + STOP_]);
      double s = 0.0;
      for (int j = 0; j < T_; ++j) s += exp(al[j] + (double)trs[j*T_ + STOP_] - mx);
      fwd[b] = mx + log(s);
    }
  } else {
    __shared__ double tr64[T_*T_];
    __shared__ double dl[T_];
    __shared__ unsigned char bp[S_][T_];
    __shared__ int msk[S_];
    for (int i = lane; i < T_*T_; i += 64) tr64[i] = (double)trans[i];
    __syncthreads();
    if (lane < T_) dl[lane] = (double)emitp[(size_t)b*S_*T_ + lane] + tr64[START_*T_ + lane];
    if (lane == 0) msk[0] = maskp[b*S_];
    __syncthreads();
    float ce = emitp[((size_t)b*S_ + 1)*T_ + kk];
    int   cm = maskp[b*S_ + 1];
    for (int t = 1; t < S_; ++t) {
      float ne = 0.f; int nm = 0;
      if (t+1 < S_) { ne = emitp[((size_t)b*S_ + t + 1)*T_ + kk]; nm = maskp[b*S_ + t + 1]; }
      double best = dl[p*11] + tr64[(p*11)*T_ + kk];
      int arg = p*11;
      #pragma unroll
      for (int u = 1; u < 11; ++u) {
        const int j = p*11 + u;
        const double sc = dl[j] + tr64[j*T_ + kk];
        if (sc > best) { best = sc; arg = j; }
      }
      const double ob = __shfl_xor(best, 32);
      const int    oa = __shfl_xor(arg, 32);
      if (p == 0 && ob > best) { best = ob; arg = oa; }
      __syncthreads();
      if (p == 0 && k < T_) {
        if (cm) { dl[k] = best + (double)ce; bp[t][k] = (unsigned char)arg; }
        else    { bp[t][k] = (unsigned char)k; }
      }
      if (lane == 0) msk[t] = cm;
      __syncthreads();
      ce = ne; cm = nm;
    }
    if (lane == 0) {
      double bb = dl[0] + tr64[STOP_]; int cur = 0;
      for (int j = 1; j < T_; ++j) { const double sc = dl[j] + tr64[j*T_ + STOP_]; if (sc > bb) { bb = sc; cur = j; } }
      for (int t = S_-1; ; --t) {
        out_tags[b*S_ + t] = (float)(cur * msk[t]);
        if (t == 0) break;
        cur = bp[t][cur];
      }
    }
  }
}

__global__ void finalize_kernel(const double* __restrict__ fwd, const double* __restrict__ gold, float* __restrict__ out){
  if (threadIdx.x == 0 && blockIdx.x == 0) {
    double s = 0.0, g = 0.0;
    for (int b = 0; b < B_; ++b) { s += fwd[b]; g += gold[b]; }
    out[0] = (float)((s - g) / (double)B_);
  }
}

extern "C" void kernel_launch(void* const* d_in, const int* in_sizes, int n_in,
                              void* d_out, int out_size, void* d_ws, size_t ws_size,
                              hipStream_t stream) {
  const int*   word   = (const int*)d_in[0];
  const int*   maskp  = (const int*)d_in[1];
  const int*   labels = (const int*)d_in[2];
  const float* emb    = (const float*)d_in[3];
  const float* w_ih_f = (const float*)d_in[4];
  const float* w_hh_f = (const float*)d_in[5];
  const float* b_f    = (const float*)d_in[6];
  const float* w_ih_b = (const float*)d_in[7];
  const float* w_hh_b = (const float*)d_in[8];
  const float* b_b    = (const float*)d_in[9];
  const float* hw_W   = (const float*)d_in[10];
  const float* hw_b   = (const float*)d_in[11];
  const float* out_W  = (const float*)d_in[12];
  const float* out_b  = (const float*)d_in[13];
  const float* trans  = (const float*)d_in[14];
  float* out = (float*)d_out;

  // workspace layout (~88.6 MB)
  float* h_bi  = (float*)d_ws;                          // [32768,512] -> h2 in place
  float* buf0  = h_bi + 16777216ULL;                    // [2,1024,1024] gates ping
  float* buf1  = buf0 + 2097152ULL;                     // [2,1024,1024] gates pong
  __half* wT16 = (__half*)(buf1 + 2097152ULL);          // [2][1024 col][256 k] fp16
  float* emitp = (float*)(wT16 + 524288ULL);            // [32768,22]
  float* stH   = emitp + 720896ULL;                     // [2,64,256]
  float* stC   = stH + 32768ULL;                        // [2,64,256]
  unsigned long long* hx = (unsigned long long*)(stC + 32768ULL);  // [2 par][32 g][4 b][256]
  double* fwdp = (double*)(hx + 65536ULL);              // [64]
  double* goldp = fwdp + 64;                            // [64]

  hipMemsetAsync(hx, 0, 65536ULL * 8, stream);          // clear tags (replay safety)

  wtr16_kernel<<<1024, 256, 0, stream>>>(w_hh_f, wT16);
  wtr16_kernel<<<1024, 256, 0, stream>>>(w_hh_b, wT16 + 262144ULL);

  // chunk 0 gates -> buf0
  gemm_gates<<<dim3(CROWS/64, 16, 2), 256, 0, stream>>>(
      word, maskp, emb, w_ih_f, b_f, w_ih_b, b_b, buf0, 0, S_ - C_);

  // fused recurrence + next-chunk gates
  for (int i = 0; i < NCH; ++i) {
    const int t0f = i * C_;
    const int t0b = S_ - (i + 1) * C_;
    const int n0f = (i < NCH-1) ? (i + 1) * C_ : -1;
    const int n0b = S_ - (i + 2) * C_;
    float* gcur = (i & 1) ? buf1 : buf0;
    float* gnext = (i & 1) ? buf0 : buf1;
    lstm_mega<<<512, 256, 0, stream>>>(
        gcur, gnext, word, maskp, emb, w_ih_f, b_f, w_ih_b, b_b,
        wT16, h_bi, stH, stC, hx, t0f, t0b, n0f, n0b, i*(C_-1), (i == 0) ? 1 : 0);
  }

  // highway in row chunks (proj into buf0..buf1 contiguous), h2 in place
  for (int rc = 0; rc < M_ / RCH; ++rc) {
    float* Ach = h_bi + (size_t)rc * RCH * 512;
    gemm_tiled<<<dim3(RCH/64, 16), 256, 0, stream>>>(
        Ach, nullptr, nullptr, nullptr, hw_W, hw_b, buf0, 2*H_, G4_, 0, 0, C_);
    highway_kernel<<<(RCH*512)/256, 256, 0, stream>>>(buf0, Ach);
  }

  // emissions
  gemm_tiled<<<dim3(M_/64, 1), 256, 0, stream>>>(
      h_bi, nullptr, nullptr, nullptr, out_W, out_b, emitp, 2*H_, T_, 0, 0, C_);

  // CRF
  gold_kernel<<<64, 256, 0, stream>>>(labels, maskp, emitp, trans, goldp);
  crf_vit_kernel<<<dim3(64, 2), 64, 0, stream>>>(emitp, trans, maskp, fwdp, out + 1);
  finalize_kernel<<<1, 64, 0, stream>>>(fwdp, goldp, out);
}